// Round 7
// baseline (916105.664 us; speedup 1.0000x reference)
//
#include <hip/hip_runtime.h>
#include <stdint.h>

#define HID 1024
#define NLAYERS 8
#define NLET 100
#define T_TOTAL 4096

typedef uint32_t u32x4 __attribute__((ext_vector_type(4)));

// ---------- helpers ----------
__device__ __forceinline__ uint32_t f2bf(float f) {
    uint32_t u = __float_as_uint(f);
    return (u + 0x7FFFu + ((u >> 16) & 1u)) >> 16;
}
__device__ __forceinline__ float bflo(uint32_t p) { return __uint_as_float(p << 16); }
__device__ __forceinline__ float bfhi(uint32_t p) { return __uint_as_float(p & 0xFFFF0000u); }
__device__ __forceinline__ float sigm(float x) { return 1.0f / (1.0f + __expf(-x)); }
__device__ __forceinline__ float tanh_f(float x) {
    float xx = fminf(fmaxf(x, -15.0f), 15.0f);
    float e = __expf(2.0f * xx);
    return (e - 1.0f) / (e + 1.0f);
}
// signed byte b (0..3) of word w, as float
#define SBYTE(w, b) ((float)((int)((w) << (24 - 8 * (b))) >> 24))
// round fp32 bit pattern to 24-bit (drop low 8 mantissa bits, round-half-up).
__device__ __forceinline__ uint32_t rnd24(float f) {
    return (__float_as_uint(f) + 0x80u) >> 8;
}

// device-coherent (bypass L1+L2, visible across XCDs) ops
__device__ __forceinline__ void store_coh_x4(void* p, u32x4 d) {
    asm volatile("global_store_dwordx4 %0, %1, off sc0 sc1" ::"v"(p), "v"(d) : "memory");
}
__device__ __forceinline__ void load_coh_x4(const void* p, u32x4& a) {
    asm volatile(
        "global_load_dwordx4 %0, %1, off sc0 sc1\n\t"
        "s_waitcnt vmcnt(0)"
        : "=v"(a) : "v"(p) : "memory");
}
// 64-B coherent load (relay's central poll)
__device__ __forceinline__ void load_coh_64(const void* p, u32x4& a, u32x4& b, u32x4& c,
                                            u32x4& d) {
    asm volatile(
        "global_load_dwordx4 %0, %4, off sc0 sc1\n\t"
        "global_load_dwordx4 %1, %4, off offset:16 sc0 sc1\n\t"
        "global_load_dwordx4 %2, %4, off offset:32 sc0 sc1\n\t"
        "global_load_dwordx4 %3, %4, off offset:48 sc0 sc1\n\t"
        "s_waitcnt vmcnt(0)"
        : "=v"(a), "=v"(b), "=v"(c), "=v"(d) : "v"(p) : "memory");
}
// L2-coherent (same-XCD) ops: sc0 only -- bypass L1, stay in this XCD's L2
__device__ __forceinline__ void store_l2_x4(void* p, u32x4 d) {
    asm volatile("global_store_dwordx4 %0, %1, off sc0" ::"v"(p), "v"(d) : "memory");
}
__device__ __forceinline__ void load_l2_x4(const void* p, u32x4& a) {
    asm volatile(
        "global_load_dwordx4 %0, %1, off sc0\n\t"
        "s_waitcnt vmcnt(0)"
        : "=v"(a) : "v"(p) : "memory");
}

// ---------- kernel 1: persistent stacked-LSTM scan ----------
// 256 blocks x 256 threads (4 waves), 1 block/CU. Block b owns units {4b..4b+3};
// wave u owns unit k=4b+u for ALL 8 layers. (R5's best-measured compute shape.)
// Precision: h-weights = packed bf16 pairs in regs + int8 residual (scale 2^-20) in
// LDS (128 KiB) -> effective weight error <= 2^-21. x-weights exact fp32 in regs.
// Chunk: 16-B self-contained (4 x 24-bit h + 32-bit step tag).
//
// XCD-HIERARCHICAL BROADCAST (R6 post-mortem: every block re-read all 256 chunks
// over the sc1 fabric path every step -> ~2.9 MB/step at HBM service latency):
//  1) each block's thread 0 stores its chunk ONCE to the central board (sc0 sc1)
//  2) ONE RELAY BLOCK PER XCD (elected at startup: s_getreg(HW_REG_XCC_ID) groups
//     blocks by PHYSICAL XCD; rank-0 of each group is relay) polls the central
//     board (8 x 4 KB/step instead of 256 x 4 KB) and republishes raw chunks to an
//     XCD-local board with sc0-only stores (stays in the local L2)
//  3) all blocks consume from their XCD-local board with sc0-only loads: L2
//     latency, no fabric/HBM traffic, per-thread 16-B chunks (R5's conflict-free
//     unpack pattern)
// Correctness does NOT depend on XCD placement: tags discriminate stale data, and
// a consumer falls back to the always-correct central board (sc1) after 128 local
// retries -- wrong grouping costs speed only.
// Overwrite safety: producer publishes central s+2 only after consuming s+1, which
// requires its relay read ALL central s+1, which requires every block pushed s+1,
// which requires every relay read central s. Same chain for local boards.
__global__ void __launch_bounds__(256, 1)
lstm_persistent(const float* __restrict__ website, const float* __restrict__ payload,
                const float* __restrict__ W_ih, const float* __restrict__ W_hh,
                const float* __restrict__ b_ih, const float* __restrict__ b_hh,
                char* central, char* localb, int* counters, float* c_out) {
    __shared__ float h_lds[HID];
    __shared__ float h_new[4];
    __shared__ int s_xcc, s_relay;
    extern __shared__ __align__(16) uint8_t res_lds[];  // 4*8*4*64*16 = 128 KiB

    const int tid = threadIdx.x;    // 0..255
    const int b = blockIdx.x;       // 0..255
    const int u = tid >> 6;         // wave 0..3 = unit within block
    const int lane = tid & 63;
    const int k = b * 4 + u;        // global hidden unit

    // ---- one-time: pack weights (bf16 hi in regs, int8 residual in LDS) ----
    uint32_t wh[NLAYERS][4][8];
    float wxf[NLAYERS][4][2];
    float bias[NLAYERS][4];
#pragma unroll
    for (int l = 0; l < NLAYERS; ++l) {
#pragma unroll
        for (int g = 0; g < 4; ++g) {
            const int row = 1024 * g + k;
            const float* src = W_hh + ((size_t)(l * 4096 + row)) * 1024;
            uint32_t rb[4];
#pragma unroll
            for (int p = 0; p < 8; ++p) {
                const int c0 = 2 * lane + 128 * p;
                const float w0 = src[c0], w1 = src[c0 + 1];
                const uint32_t pk = f2bf(w0) | (f2bf(w1) << 16);
                wh[l][g][p] = pk;
                const float r0 = (w0 - bflo(pk)) * 1048576.0f;
                const float r1 = (w1 - bfhi(pk)) * 1048576.0f;
                const int i0 = __float2int_rn(fminf(fmaxf(r0, -127.0f), 127.0f));
                const int i1 = __float2int_rn(fminf(fmaxf(r1, -127.0f), 127.0f));
                const uint32_t byt = ((uint32_t)i0 & 0xFFu) | (((uint32_t)i1 & 0xFFu) << 8);
                if ((p & 1) == 0) rb[p >> 1] = byt;
                else rb[p >> 1] |= (byt << 16);
            }
            {
                u32x4 v;
                v.x = rb[0]; v.y = rb[1]; v.z = rb[2]; v.w = rb[3];
                u32x4* dst = (u32x4*)res_lds + (((u * NLAYERS + l) * 4 + g) * 64 + lane);
                *dst = v;
            }
            if (lane < 50) {
                const float* sx = W_ih + ((size_t)(l * 4096 + row)) * NLET + 2 * lane;
                wxf[l][g][0] = sx[0];
                wxf[l][g][1] = sx[1];
            } else {
                wxf[l][g][0] = 0.f;
                wxf[l][g][1] = 0.f;
            }
            bias[l][g] = b_ih[l * 4096 + row] + b_hh[l * 4096 + row];
        }
    }

    // ---- relay election by PHYSICAL XCD ----
    if (tid == 0) {
        // s_getreg imm = id | (offset<<6) | ((width-1)<<11); HW_REG_XCC_ID id=20
        int xcc = __builtin_amdgcn_s_getreg(20 | (0 << 6) | (31 << 11)) & 7;
        s_xcc = xcc;
        s_relay = (atomicAdd(&counters[xcc], 1) == 0) ? 1 : 0;
    }

    // init h(0)=0, c(0)=0
    ((float4*)h_lds)[tid] = make_float4(0.f, 0.f, 0.f, 0.f);
    float c = 0.0f;
    int dl = 6;  // relay's adaptive central-poll delay, units of s_sleep(8) ~0.24us
    __syncthreads();
    const int myxcc = s_xcc;
    const int relay = s_relay;

    for (int t = 0; t < T_TOTAL; ++t) {
        float x0 = 0.f, x1 = 0.f;
        if (lane < 50) {
            const float* xp = (t < 2048) ? (website + (size_t)t * NLET)
                                         : (payload + (size_t)(t - 2048) * NLET);
            x0 = xp[2 * lane];
            x1 = xp[2 * lane + 1];
        }
#pragma unroll
        for (int l = 0; l < NLAYERS; ++l) {
            const int s = t * NLAYERS + l + 1;  // step being produced (1..32768)
            const int par = s & 1;

            // ---- compute this wave's unit: 4 gate dot-products over h + x ----
            float2 hv[8];
#pragma unroll
            for (int p = 0; p < 8; ++p)
                hv[p] = *(const float2*)&h_lds[2 * lane + 128 * p];
            const u32x4* rr = (const u32x4*)res_lds + ((u * NLAYERS + l) * 4) * 64 + lane;
            const u32x4 rg0 = rr[0];
            const u32x4 rg1 = rr[64];
            const u32x4 rg2 = rr[128];
            const u32x4 rg3 = rr[192];

            float acc0 = 0.f, acc1 = 0.f, acc2 = 0.f, acc3 = 0.f;
#pragma unroll
            for (int p = 0; p < 8; ++p) {
                const float hA = hv[p].x, hB = hv[p].y;
                uint32_t w;
                w = wh[l][0][p]; acc0 = fmaf(bflo(w), hA, acc0); acc0 = fmaf(bfhi(w), hB, acc0);
                w = wh[l][1][p]; acc1 = fmaf(bflo(w), hA, acc1); acc1 = fmaf(bfhi(w), hB, acc1);
                w = wh[l][2][p]; acc2 = fmaf(bflo(w), hA, acc2); acc2 = fmaf(bfhi(w), hB, acc2);
                w = wh[l][3][p]; acc3 = fmaf(bflo(w), hA, acc3); acc3 = fmaf(bfhi(w), hB, acc3);
            }
            float ra0 = 0.f, ra1 = 0.f, ra2 = 0.f, ra3 = 0.f;
#pragma unroll
            for (int p = 0; p < 8; ++p) {
                const float hA = hv[p].x, hB = hv[p].y;
                const int b0 = 2 * (p & 1), b1 = 2 * (p & 1) + 1;
                uint32_t w;
                w = rg0[p >> 1]; ra0 = fmaf(SBYTE(w, b0), hA, ra0); ra0 = fmaf(SBYTE(w, b1), hB, ra0);
                w = rg1[p >> 1]; ra1 = fmaf(SBYTE(w, b0), hA, ra1); ra1 = fmaf(SBYTE(w, b1), hB, ra1);
                w = rg2[p >> 1]; ra2 = fmaf(SBYTE(w, b0), hA, ra2); ra2 = fmaf(SBYTE(w, b1), hB, ra2);
                w = rg3[p >> 1]; ra3 = fmaf(SBYTE(w, b0), hA, ra3); ra3 = fmaf(SBYTE(w, b1), hB, ra3);
            }
            acc0 = fmaf(ra0, 0x1.0p-20f, acc0);
            acc1 = fmaf(ra1, 0x1.0p-20f, acc1);
            acc2 = fmaf(ra2, 0x1.0p-20f, acc2);
            acc3 = fmaf(ra3, 0x1.0p-20f, acc3);
            acc0 = fmaf(wxf[l][0][0], x0, acc0); acc0 = fmaf(wxf[l][0][1], x1, acc0);
            acc1 = fmaf(wxf[l][1][0], x0, acc1); acc1 = fmaf(wxf[l][1][1], x1, acc1);
            acc2 = fmaf(wxf[l][2][0], x0, acc2); acc2 = fmaf(wxf[l][2][1], x1, acc2);
            acc3 = fmaf(wxf[l][3][0], x0, acc3); acc3 = fmaf(wxf[l][3][1], x1, acc3);

#pragma unroll
            for (int mm = 32; mm > 0; mm >>= 1) {
                acc0 += __shfl_xor(acc0, mm, 64);
                acc1 += __shfl_xor(acc1, mm, 64);
                acc2 += __shfl_xor(acc2, mm, 64);
                acc3 += __shfl_xor(acc3, mm, 64);
            }
            const float gi = sigm(acc0 + bias[l][0]);
            const float gf = sigm(acc1 + bias[l][1]);
            const float gg = tanh_f(acc2 + bias[l][2]);
            const float go = sigm(acc3 + bias[l][3]);
            c = fmaf(gf, c, gi * gg);
            const float hn = go * tanh_f(c);
            if (lane == 0) h_new[u] = hn;
            __syncthreads();  // h_new ready; everyone done reading h_lds

            // ---- push: ONE 16-B chunk per block to the central board ----
            if (tid == 0) {
                const uint32_t t0 = rnd24(h_new[0]);
                const uint32_t t1 = rnd24(h_new[1]);
                const uint32_t t2 = rnd24(h_new[2]);
                const uint32_t t3 = rnd24(h_new[3]);
                u32x4 d;
                d.x = (t0 << 8) | (t1 >> 16);
                d.y = (t1 << 16) | (t2 >> 8);
                d.z = (t2 << 24) | t3;
                d.w = (uint32_t)s;
                store_coh_x4(central + ((size_t)(par * 256 + b)) * 16, d);
            }

            // ---- relay (wave 0 of one block per XCD): central poll + republish ----
            if (relay && tid < 64) {
                const char* cen = central + ((size_t)(par * 256 + 4 * lane)) * 16;
                for (int i = 0; i < dl; ++i) __builtin_amdgcn_s_sleep(8);
                u32x4 a0, a1, a2, a3;
                int retries = 0;
                for (;;) {
                    load_coh_64(cen, a0, a1, a2, a3);
                    if (a0.w == (uint32_t)s && a1.w == (uint32_t)s &&
                        a2.w == (uint32_t)s && a3.w == (uint32_t)s)
                        break;
                    ++retries;
                    __builtin_amdgcn_s_sleep(8);
                }
                dl = (retries == 0) ? (dl > 0 ? dl - 1 : 0)
                                    : ((dl + retries > 48) ? 48 : dl + retries);
                char* loc = localb + ((size_t)((myxcc * 2 + par) * 256 + 4 * lane)) * 16;
                store_l2_x4(loc, a0);
                store_l2_x4(loc + 16, a1);
                store_l2_x4(loc + 32, a2);
                store_l2_x4(loc + 48, a3);
            }

            // ---- consume: every thread polls its chunk on the XCD-local board ----
            {
                const char* lp =
                    localb + ((size_t)((myxcc * 2 + par) * 256 + tid)) * 16;
                const char* cp = central + ((size_t)(par * 256 + tid)) * 16;
                u32x4 a;
                int r = 0;
                for (;;) {
                    if (r < 128) load_l2_x4(lp, a);   // cheap same-XCD L2 poll
                    else         load_coh_x4(cp, a);  // fallback: central (always correct)
                    if (a.w == (uint32_t)s) break;
                    ++r;
                    __builtin_amdgcn_s_sleep(2);
                }
                h_lds[4 * tid + 0] = __uint_as_float(a.x & 0xFFFFFF00u);
                h_lds[4 * tid + 1] = __uint_as_float(((a.x & 0xFFu) << 24) | ((a.y >> 16) << 8));
                h_lds[4 * tid + 2] = __uint_as_float(((a.y & 0xFFFFu) << 16) | ((a.z >> 24) << 8));
                h_lds[4 * tid + 3] = __uint_as_float((a.z & 0xFFFFFFu) << 8);
            }
            __syncthreads();  // h_lds now holds h(s)
        }
    }

    if (lane == 0) c_out[k] = c;
}

// ---------- kernel 2: head — out = sigmoid(W_out @ (W_lin@c + b_lin) + b_out) ----------
__global__ void head_kernel(const float* __restrict__ c_out, const float* __restrict__ W_lin,
                            const float* __restrict__ b_lin, const float* __restrict__ W_out,
                            const float* __restrict__ b_out, float* out) {
    const int lane = threadIdx.x;  // 64 threads, one wave
    float cv[16];
    const float4* cp = (const float4*)(c_out + lane * 16);
#pragma unroll
    for (int q = 0; q < 4; ++q) {
        float4 v = cp[q];
        cv[4 * q + 0] = v.x;
        cv[4 * q + 1] = v.y;
        cv[4 * q + 2] = v.z;
        cv[4 * q + 3] = v.w;
    }
    float fsum = 0.f;
#pragma unroll
    for (int i = 0; i < 16; ++i) {
        const float* w = W_lin + (size_t)i * HID + lane * 16;
        float a = 0.f;
#pragma unroll
        for (int m = 0; m < 16; ++m) a = fmaf(w[m], cv[m], a);
#pragma unroll
        for (int mm = 32; mm > 0; mm >>= 1) a += __shfl_xor(a, mm, 64);
        fsum = fmaf(W_out[i], a + b_lin[i], fsum);
    }
    if (lane == 0) out[0] = sigm(fsum + b_out[0]);
}

extern "C" void kernel_launch(void* const* d_in, const int* in_sizes, int n_in, void* d_out,
                              int out_size, void* d_ws, size_t ws_size, hipStream_t stream) {
    (void)in_sizes; (void)n_in; (void)out_size; (void)ws_size;
    const float* website = (const float*)d_in[0];
    const float* payload = (const float*)d_in[1];
    const float* W_ih = (const float*)d_in[2];
    const float* W_hh = (const float*)d_in[3];
    const float* b_ih = (const float*)d_in[4];
    const float* b_hh = (const float*)d_in[5];
    const float* W_lin = (const float*)d_in[6];
    const float* b_lin = (const float*)d_in[7];
    const float* W_out = (const float*)d_in[8];
    const float* b_out = (const float*)d_in[9];

    // workspace layout:
    //   central board : 2(par) * 256 * 16 B                     =  8 KiB  @ 0
    //   local boards  : 8(xcd) * 2(par) * 256 * 16 B            = 64 KiB  @ 8192
    //   counters      : 8 * int (election)                      =  32 B   @ 73728
    //   c_out         : 1024 floats                             =  4 KiB  @ 73984
    char* central = (char*)d_ws;
    char* localb = (char*)d_ws + 8192;
    int* counters = (int*)((char*)d_ws + 73728);
    float* c_out = (float*)((char*)d_ws + 73984);

    hipMemsetAsync(d_ws, 0, 73760, stream);  // zero boards + counters (s starts at 1)
    // 128 KiB dynamic LDS for int8 weight residuals
    lstm_persistent<<<256, 256, 131072, stream>>>(website, payload, W_ih, W_hh, b_ih, b_hh,
                                                  central, localb, counters, c_out);
    head_kernel<<<1, 64, 0, stream>>>(c_out, W_lin, b_lin, W_out, b_out, (float*)d_out);
}

// Round 11
// 256684.351 us; speedup vs baseline: 3.5690x; 3.5690x over previous
//
#include <hip/hip_runtime.h>
#include <stdint.h>

#define HID 1024
#define NLAYERS 8
#define NLET 100
#define T_TOTAL 4096

typedef uint32_t u32x4 __attribute__((ext_vector_type(4)));

// ---------- helpers ----------
__device__ __forceinline__ uint32_t f2bf(float f) {
    uint32_t u = __float_as_uint(f);
    return (u + 0x7FFFu + ((u >> 16) & 1u)) >> 16;
}
__device__ __forceinline__ float bflo(uint32_t p) { return __uint_as_float(p << 16); }
__device__ __forceinline__ float bfhi(uint32_t p) { return __uint_as_float(p & 0xFFFF0000u); }
__device__ __forceinline__ float sigm(float x) { return 1.0f / (1.0f + __expf(-x)); }
__device__ __forceinline__ float tanh_f(float x) {
    float xx = fminf(fmaxf(x, -15.0f), 15.0f);
    float e = __expf(2.0f * xx);
    return (e - 1.0f) / (e + 1.0f);
}
// signed byte b (0..3) of word w, as float
#define SBYTE(w, b) ((float)((int)((w) << (24 - 8 * (b))) >> 24))
// round fp32 bit pattern to 24-bit (drop low 8 mantissa bits, round-half-up).
// |h|<1 (tanh-bounded) so the +0x80 carry stays inside the same sign monotone range.
__device__ __forceinline__ uint32_t rnd24(float f) {
    return (__float_as_uint(f) + 0x80u) >> 8;
}

// device-coherent (bypass L1+L2) ops -- the ONLY trusted publish primitives
// (R8-R10: every shared-line/atomic gate variant aborted; per-thread
// distinct-address sc0sc1 tagged loads are proven across R1/R4/R5).
__device__ __forceinline__ void store_coh_x4(void* p, u32x4 d) {
    asm volatile("global_store_dwordx4 %0, %1, off sc0 sc1" ::"v"(p), "v"(d) : "memory");
}
__device__ __forceinline__ void load_coh_x4(const void* p, u32x4& a) {
    asm volatile(
        "global_load_dwordx4 %0, %1, off sc0 sc1\n\t"
        "s_waitcnt vmcnt(0)"
        : "=v"(a) : "v"(p) : "memory");
}
__device__ __forceinline__ uint32_t load_coh_u32(const void* p) {
    uint32_t a;
    asm volatile(
        "global_load_dword %0, %1, off sc0 sc1\n\t"
        "s_waitcnt vmcnt(0)"
        : "=v"(a) : "v"(p) : "memory");
    return a;
}

// ---------- kernel 1: persistent stacked-LSTM scan ----------
// 256 blocks x 256 threads (4 waves), 1 block/CU. Block b owns units {4b..4b+3};
// wave u owns unit k=4b+u for ALL 8 layers. (R5's passing structure, verbatim
// except the poll section.)
// Precision: h-weights = packed bf16 pairs in regs + int8 residual (scale 2^-20) in
// LDS (128 KiB) -> effective weight error <= 2^-21. x-weights exact fp32 in regs.
// Mailbox: 16-B self-contained chunk (4 x 24-bit h + 32-bit step tag), 64 replica
// copies. mail layout: [(copy*2 + parity)*256 + producer] * 16 bytes.
//
// SENTINEL RELEASE (replaces R5's adaptive pacing, which decrements on every hit
// and therefore converges to ~50% miss oscillation -> measured 2.8 loads/chunk):
//   after the push, lane 0 of each wave polls JUST THE TAG DWORD of one
//   spread-out remote chunk ((b+51+64u)&255) with the in-chain == s loop;
//   __syncthreads() then releases the volley: each thread issues ONE 16-B read,
//   tag-verified, with the proven in-chain straggler loop.
// In-chain proof (R4, holds for ANY chunk q read by block X at step s): block q
// pushes s+2 (overwriting parity slot of s) only after q consumed s+1, which
// requires ALL blocks pushed s+1, including X -- but X pushes s+1 only after it
// consumed s. So while X waits at step s, slot tags are in {s-2, s}: == s loops
// terminate. The ONLY loops in this kernel are these in-chain polls.
__global__ void __launch_bounds__(256, 1)
lstm_persistent(const float* __restrict__ website, const float* __restrict__ payload,
                const float* __restrict__ W_ih, const float* __restrict__ W_hh,
                const float* __restrict__ b_ih, const float* __restrict__ b_hh,
                char* mail, float* c_out, int ncopies) {
    __shared__ float h_lds[HID];
    __shared__ float h_new[4];
    extern __shared__ __align__(16) uint8_t res_lds[];  // 4*8*4*64*16 = 128 KiB

    const int tid = threadIdx.x;    // 0..255
    const int b = blockIdx.x;       // 0..255
    const int u = tid >> 6;         // wave 0..3 = unit within block
    const int lane = tid & 63;
    const int k = b * 4 + u;        // global hidden unit
    const int rcopy = b & (ncopies - 1);

    // ---- one-time: pack weights (bf16 hi in regs, int8 residual in LDS) ----
    uint32_t wh[NLAYERS][4][8];  // [layer][gate][pair p] -> cols (2L+128p, 2L+128p+1)
    float wxf[NLAYERS][4][2];    // exact fp32 x-weights (cols 2L, 2L+1), zero for lanes >= 50
    float bias[NLAYERS][4];
#pragma unroll
    for (int l = 0; l < NLAYERS; ++l) {
#pragma unroll
        for (int g = 0; g < 4; ++g) {
            const int row = 1024 * g + k;
            const float* src = W_hh + ((size_t)(l * 4096 + row)) * 1024;
            uint32_t rb[4];
#pragma unroll
            for (int p = 0; p < 8; ++p) {
                const int c0 = 2 * lane + 128 * p;
                const float w0 = src[c0], w1 = src[c0 + 1];
                const uint32_t pk = f2bf(w0) | (f2bf(w1) << 16);
                wh[l][g][p] = pk;
                // residual, quantized at scale 2^-20 (max |r| = 6.1e-5 < 127*2^-20)
                const float r0 = (w0 - bflo(pk)) * 1048576.0f;
                const float r1 = (w1 - bfhi(pk)) * 1048576.0f;
                const int i0 = __float2int_rn(fminf(fmaxf(r0, -127.0f), 127.0f));
                const int i1 = __float2int_rn(fminf(fmaxf(r1, -127.0f), 127.0f));
                const uint32_t byt = ((uint32_t)i0 & 0xFFu) | (((uint32_t)i1 & 0xFFu) << 8);
                if ((p & 1) == 0) rb[p >> 1] = byt;
                else rb[p >> 1] |= (byt << 16);
            }
            {
                u32x4 v;
                v.x = rb[0]; v.y = rb[1]; v.z = rb[2]; v.w = rb[3];
                u32x4* dst = (u32x4*)res_lds + (((u * NLAYERS + l) * 4 + g) * 64 + lane);
                *dst = v;
            }
            if (lane < 50) {
                const float* sx = W_ih + ((size_t)(l * 4096 + row)) * NLET + 2 * lane;
                wxf[l][g][0] = sx[0];
                wxf[l][g][1] = sx[1];
            } else {
                wxf[l][g][0] = 0.f;
                wxf[l][g][1] = 0.f;
            }
            bias[l][g] = b_ih[l * 4096 + row] + b_hh[l * 4096 + row];
        }
    }

    // init h(0)=0, c(0)=0
    ((float4*)h_lds)[tid] = make_float4(0.f, 0.f, 0.f, 0.f);
    float c = 0.0f;
    __syncthreads();

    for (int t = 0; t < T_TOTAL; ++t) {
        // x for this timestep (shared by all 8 layers)
        float x0 = 0.f, x1 = 0.f;
        if (lane < 50) {
            const float* xp = (t < 2048) ? (website + (size_t)t * NLET)
                                         : (payload + (size_t)(t - 2048) * NLET);
            x0 = xp[2 * lane];
            x1 = xp[2 * lane + 1];
        }
#pragma unroll
        for (int l = 0; l < NLAYERS; ++l) {
            const int s = t * NLAYERS + l + 1;  // step being produced (1..32768)
            const int par = s & 1;

            // ---- compute this wave's unit: 4 gate dot-products over h + x ----
            float2 hv[8];
#pragma unroll
            for (int p = 0; p < 8; ++p)
                hv[p] = *(const float2*)&h_lds[2 * lane + 128 * p];
            const u32x4* rr = (const u32x4*)res_lds + ((u * NLAYERS + l) * 4) * 64 + lane;
            const u32x4 rg0 = rr[0];
            const u32x4 rg1 = rr[64];
            const u32x4 rg2 = rr[128];
            const u32x4 rg3 = rr[192];

            // ---- bf16 hi-part dot products ----
            float acc0 = 0.f, acc1 = 0.f, acc2 = 0.f, acc3 = 0.f;
#pragma unroll
            for (int p = 0; p < 8; ++p) {
                const float hA = hv[p].x, hB = hv[p].y;
                uint32_t w;
                w = wh[l][0][p]; acc0 = fmaf(bflo(w), hA, acc0); acc0 = fmaf(bfhi(w), hB, acc0);
                w = wh[l][1][p]; acc1 = fmaf(bflo(w), hA, acc1); acc1 = fmaf(bfhi(w), hB, acc1);
                w = wh[l][2][p]; acc2 = fmaf(bflo(w), hA, acc2); acc2 = fmaf(bfhi(w), hB, acc2);
                w = wh[l][3][p]; acc3 = fmaf(bflo(w), hA, acc3); acc3 = fmaf(bfhi(w), hB, acc3);
            }
            // ---- int8 residual correction (scale 2^-20) ----
            float ra0 = 0.f, ra1 = 0.f, ra2 = 0.f, ra3 = 0.f;
#pragma unroll
            for (int p = 0; p < 8; ++p) {
                const float hA = hv[p].x, hB = hv[p].y;
                const int b0 = 2 * (p & 1), b1 = 2 * (p & 1) + 1;
                uint32_t w;
                w = rg0[p >> 1]; ra0 = fmaf(SBYTE(w, b0), hA, ra0); ra0 = fmaf(SBYTE(w, b1), hB, ra0);
                w = rg1[p >> 1]; ra1 = fmaf(SBYTE(w, b0), hA, ra1); ra1 = fmaf(SBYTE(w, b1), hB, ra1);
                w = rg2[p >> 1]; ra2 = fmaf(SBYTE(w, b0), hA, ra2); ra2 = fmaf(SBYTE(w, b1), hB, ra2);
                w = rg3[p >> 1]; ra3 = fmaf(SBYTE(w, b0), hA, ra3); ra3 = fmaf(SBYTE(w, b1), hB, ra3);
            }
            acc0 = fmaf(ra0, 0x1.0p-20f, acc0);
            acc1 = fmaf(ra1, 0x1.0p-20f, acc1);
            acc2 = fmaf(ra2, 0x1.0p-20f, acc2);
            acc3 = fmaf(ra3, 0x1.0p-20f, acc3);
            // ---- exact fp32 x contribution ----
            acc0 = fmaf(wxf[l][0][0], x0, acc0); acc0 = fmaf(wxf[l][0][1], x1, acc0);
            acc1 = fmaf(wxf[l][1][0], x0, acc1); acc1 = fmaf(wxf[l][1][1], x1, acc1);
            acc2 = fmaf(wxf[l][2][0], x0, acc2); acc2 = fmaf(wxf[l][2][1], x1, acc2);
            acc3 = fmaf(wxf[l][3][0], x0, acc3); acc3 = fmaf(wxf[l][3][1], x1, acc3);

#pragma unroll
            for (int mm = 32; mm > 0; mm >>= 1) {
                acc0 += __shfl_xor(acc0, mm, 64);
                acc1 += __shfl_xor(acc1, mm, 64);
                acc2 += __shfl_xor(acc2, mm, 64);
                acc3 += __shfl_xor(acc3, mm, 64);
            }
            const float gi = sigm(acc0 + bias[l][0]);
            const float gf = sigm(acc1 + bias[l][1]);
            const float gg = tanh_f(acc2 + bias[l][2]);
            const float go = sigm(acc3 + bias[l][3]);
            c = fmaf(gf, c, gi * gg);
            const float hn = go * tanh_f(c);
            if (lane == 0) h_new[u] = hn;
            __syncthreads();  // h_new ready; everyone done reading h_lds

            // ---- push: pack 4x24-bit h + tag into ONE 16-B chunk per copy ----
            if (tid < ncopies) {
                const uint32_t t0 = rnd24(h_new[0]);
                const uint32_t t1 = rnd24(h_new[1]);
                const uint32_t t2 = rnd24(h_new[2]);
                const uint32_t t3 = rnd24(h_new[3]);
                u32x4 d;
                d.x = (t0 << 8) | (t1 >> 16);
                d.y = (t1 << 16) | (t2 >> 8);
                d.z = (t2 << 24) | t3;
                d.w = (uint32_t)s;
                char* dst = mail + ((size_t)((tid * 2 + par) * 256 + b)) * 16;
                store_coh_x4(dst, d);
            }

            // ---- sentinel release: lane 0 of each wave polls ONE remote tag ----
            if (lane == 0) {
                const int sq = (b + 51 + 64 * u) & 255;  // spread; never own block
                const char* tp =
                    mail + ((size_t)((rcopy * 2 + par) * 256 + sq)) * 16 + 12;
                while (load_coh_u32(tp) != (uint32_t)s)  // in-chain: terminates
                    __builtin_amdgcn_s_sleep(8);
            }
            __syncthreads();  // release: ~all chunks now at the coherence point

            // ---- volley: ONE 16-B read per thread, tag-verified (in-chain) ----
            {
                const char* srcp = mail + ((size_t)((rcopy * 2 + par) * 256 + tid)) * 16;
                u32x4 a;
                load_coh_x4(srcp, a);
                while (a.w != (uint32_t)s) {  // straggler loop, in-chain
                    __builtin_amdgcn_s_sleep(2);
                    load_coh_x4(srcp, a);
                }
                h_lds[4 * tid + 0] = __uint_as_float(a.x & 0xFFFFFF00u);
                h_lds[4 * tid + 1] = __uint_as_float(((a.x & 0xFFu) << 24) | ((a.y >> 16) << 8));
                h_lds[4 * tid + 2] = __uint_as_float(((a.y & 0xFFFFu) << 16) | ((a.z >> 24) << 8));
                h_lds[4 * tid + 3] = __uint_as_float((a.z & 0xFFFFFFu) << 8);
            }
            __syncthreads();  // h_lds now holds h(s)
        }
    }

    if (lane == 0) c_out[k] = c;
}

// ---------- kernel 2: head — out = sigmoid(W_out @ (W_lin@c + b_lin) + b_out) ----------
__global__ void head_kernel(const float* __restrict__ c_out, const float* __restrict__ W_lin,
                            const float* __restrict__ b_lin, const float* __restrict__ W_out,
                            const float* __restrict__ b_out, float* out) {
    const int lane = threadIdx.x;  // 64 threads, one wave
    float cv[16];
    const float4* cp = (const float4*)(c_out + lane * 16);
#pragma unroll
    for (int q = 0; q < 4; ++q) {
        float4 v = cp[q];
        cv[4 * q + 0] = v.x;
        cv[4 * q + 1] = v.y;
        cv[4 * q + 2] = v.z;
        cv[4 * q + 3] = v.w;
    }
    float fsum = 0.f;
#pragma unroll
    for (int i = 0; i < 16; ++i) {
        const float* w = W_lin + (size_t)i * HID + lane * 16;
        float a = 0.f;
#pragma unroll
        for (int m = 0; m < 16; ++m) a = fmaf(w[m], cv[m], a);
#pragma unroll
        for (int mm = 32; mm > 0; mm >>= 1) a += __shfl_xor(a, mm, 64);
        fsum = fmaf(W_out[i], a + b_lin[i], fsum);
    }
    if (lane == 0) out[0] = sigm(fsum + b_out[0]);
}

extern "C" void kernel_launch(void* const* d_in, const int* in_sizes, int n_in, void* d_out,
                              int out_size, void* d_ws, size_t ws_size, hipStream_t stream) {
    (void)in_sizes; (void)n_in; (void)out_size;
    const float* website = (const float*)d_in[0];
    const float* payload = (const float*)d_in[1];
    const float* W_ih = (const float*)d_in[2];
    const float* W_hh = (const float*)d_in[3];
    const float* b_ih = (const float*)d_in[4];
    const float* b_hh = (const float*)d_in[5];
    const float* W_lin = (const float*)d_in[6];
    const float* b_lin = (const float*)d_in[7];
    const float* W_out = (const float*)d_in[8];
    const float* b_out = (const float*)d_in[9];

    // mailbox replicas: ncopies * 2(par) * 256(producers) * 16B = ncopies * 8 KiB
    int ncopies = 64;
    while (ncopies > 1 && (size_t)ncopies * 8192 + 4096 > ws_size) ncopies >>= 1;
    char* mail = (char*)d_ws;
    float* c_out = (float*)((char*)d_ws + (size_t)ncopies * 8192);

    hipMemsetAsync(mail, 0, (size_t)ncopies * 8192, stream);  // zero tags (s starts at 1)
    // 128 KiB dynamic LDS for int8 weight residuals (gfx950: 160 KiB/CU available)
    lstm_persistent<<<256, 256, 131072, stream>>>(website, payload, W_ih, W_hh, b_ih, b_hh,
                                                  mail, c_out, ncopies);
    head_kernel<<<1, 64, 0, stream>>>(c_out, W_lin, b_lin, W_out, b_out, (float*)d_out);
}